// Round 8
// baseline (44.669 us; speedup 1.0000x reference)
//
#include <hip/hip_runtime.h>
#include <hip/hip_bf16.h>

// out[e] = relu(concat(emb[src], emb[dst]) @ w1 + b1) @ w2
// Restructure: P[n][j]    = emb[n] . w1[0:128, j]  + b1[j]   (j < 64)
//              P[n][64+j] = emb[n] . w1[128:256, j]          (j < 64)
// out[e] = sum_j relu(P[src][j] + P[dst][64+j]) * w2[j]
// P via bf16 MFMA (16x16x32, swapped operands -> lane holds 4 consecutive
// P-cols of one node), stored bf16. absmax ~0.03 vs threshold 0.126.
//
// R8: native bf16 conversion (compiler emits v_cvt_pk_bf16_f32) instead of
// 5-op bit-twiddled RNE — R6 counters showed VALU:MFMA 3.4:1, conversions
// were the dominant per-tile cost. Grid 782 so each wave gets ~exactly 2
// tiles (balanced; prefetch covers tile 2's loads).

#define D_FEAT 128
#define HIDDEN 64

typedef __attribute__((ext_vector_type(8))) short v8s;   // 8 bf16 (4 VGPRs)
typedef __attribute__((ext_vector_type(4))) float f32x4; // 4 f32

// Native conversion: compiler pattern-matches pairs into v_cvt_pk_bf16_f32
// (do NOT hand-roll the RNE bit sequence — 5 VALU ops/value, was the R7
// bottleneck; and do NOT inline-asm cvt_pk — m240: -37% vs scalar cast).
__device__ inline unsigned short f2bf(float f) {
    return __builtin_bit_cast(unsigned short, __float2bfloat16(f));
}

// int64-vs-int32 detection: int64 (LE, idx < 2^31) => every odd int32 word 0.
__device__ inline bool detect_is64(const int* ts32, int lane) {
    int probe = ts32[2 * lane + 1];
    return __ballot(probe != 0) == 0ULL;
}

// ---------------------------------------------------------------------------
// Persistent precompute of P (n_nodes x 128, bf16).
__global__ void __launch_bounds__(256)
precompute_kernel(const float* __restrict__ emb, const float* __restrict__ w1,
                  const float* __restrict__ b1, unsigned short* __restrict__ P,
                  int n_nodes) {
    __shared__ unsigned short bt[16384];   // Bt[c][k] at (c*128+k)^((c&7)<<3)
    const int t    = threadIdx.x;
    const int lane = t & 63;
    const int wid  = t >> 6;
    const int sub  = lane & 15;   // node within tile / D col
    const int g    = lane >> 4;   // k-group / D row group

    // ---- build swizzled Bt from w1 (256x64 f32): thread t owns w1 row t.
    {
        const int k    = t & 127;
        const int half = t >> 7;
        const float4* src = reinterpret_cast<const float4*>(w1 + (size_t)t * 64);
#pragma unroll
        for (int j4 = 0; j4 < 16; ++j4) {
            const float4 v = src[j4];
            const int cb = half * 64 + j4 * 4;
            bt[((cb + 0) * 128 + k) ^ (((cb + 0) & 7) << 3)] = f2bf(v.x);
            bt[((cb + 1) * 128 + k) ^ (((cb + 1) & 7) << 3)] = f2bf(v.y);
            bt[((cb + 2) * 128 + k) ^ (((cb + 2) & 7) << 3)] = f2bf(v.z);
            bt[((cb + 3) * 128 + k) ^ (((cb + 3) & 7) << 3)] = f2bf(v.w);
        }
    }

    // bias regs (cols < 64 only, i.e. nj < 4): cols nj*16 + g*4 .. +3
    float4 bias[4];
#pragma unroll
    for (int nj = 0; nj < 4; ++nj)
        bias[nj] = *reinterpret_cast<const float4*>(b1 + nj * 16 + g * 4);

    __syncthreads();   // Bt ready; read-only from here (no more barriers)

    const int ntiles = (n_nodes + 15) / 16;
    const int gwave  = blockIdx.x * 4 + wid;
    const int nwave  = gridDim.x * 4;

    auto loadA = [&](float4* a, int tt) {
        int row = tt * 16 + sub;
        if (row >= n_nodes) row = n_nodes - 1;
        const float* p = emb + (size_t)row * D_FEAT + g * 8;
#pragma unroll
        for (int ks = 0; ks < 4; ++ks) {
            a[2 * ks]     = *reinterpret_cast<const float4*>(p + ks * 32);
            a[2 * ks + 1] = *reinterpret_cast<const float4*>(p + ks * 32 + 4);
        }
    };

    float4 A0[8], A1[8];
    if (gwave < ntiles) loadA(A0, gwave);

    for (int tt = gwave; tt < ntiles; tt += nwave) {
        const int tn = tt + nwave;
        if (tn < ntiles) loadA(A1, tn);   // prefetch next tile

        f32x4 acc[8];
#pragma unroll
        for (int nj = 0; nj < 8; ++nj) acc[nj] = (f32x4){0.f, 0.f, 0.f, 0.f};

#pragma unroll
        for (int ks = 0; ks < 4; ++ks) {
            const int k0 = ks * 32;
            const float4 a0 = A0[2 * ks], a1 = A0[2 * ks + 1];
            v8s af;
            af[0] = (short)f2bf(a0.x); af[1] = (short)f2bf(a0.y);
            af[2] = (short)f2bf(a0.z); af[3] = (short)f2bf(a0.w);
            af[4] = (short)f2bf(a1.x); af[5] = (short)f2bf(a1.y);
            af[6] = (short)f2bf(a1.z); af[7] = (short)f2bf(a1.w);
#pragma unroll
            for (int nj = 0; nj < 8; ++nj) {
                const int c = nj * 16 + sub;
                const int eidx = (c * 128 + k0 + g * 8) ^ ((c & 7) << 3);
                const v8s bf = *reinterpret_cast<const v8s*>(&bt[eidx]);
                // swapped: D[c][node], col=node=sub, row=c_local=g*4+reg
                acc[nj] = __builtin_amdgcn_mfma_f32_16x16x32_bf16(bf, af, acc[nj], 0, 0, 0);
            }
        }

        // epilogue: lane holds P cols nj*16+g*4..+3 for node tt*16+sub
        const int node = tt * 16 + sub;
        if (node < n_nodes) {
#pragma unroll
            for (int nj = 0; nj < 8; ++nj) {
                float b0 = 0.f, b1v = 0.f, b2 = 0.f, b3 = 0.f;
                if (nj < 4) { b0 = bias[nj].x; b1v = bias[nj].y;
                              b2 = bias[nj].z; b3 = bias[nj].w; }
                ushort4 o;
                o.x = f2bf(acc[nj][0] + b0);
                o.y = f2bf(acc[nj][1] + b1v);
                o.z = f2bf(acc[nj][2] + b2);
                o.w = f2bf(acc[nj][3] + b3);
                *reinterpret_cast<ushort4*>(P + (size_t)node * 128 + nj * 16 + g * 4) = o;
            }
        }

#pragma unroll
        for (int i = 0; i < 8; ++i) A0[i] = A1[i];
    }
}

// ---------------------------------------------------------------------------
// Edge pass: 8 lanes per edge, 8 edges per wave. 16B uint4 loads per half,
// bf16 unpack via bit ops, 3-step shuffle reduce. (measured ~9.3 us warm)
__device__ inline float pairterm(unsigned aw, unsigned bw, float w0, float w1) {
    float a0 = __builtin_bit_cast(float, aw << 16);
    float a1 = __builtin_bit_cast(float, aw & 0xFFFF0000u);
    float b0 = __builtin_bit_cast(float, bw << 16);
    float b1 = __builtin_bit_cast(float, bw & 0xFFFF0000u);
    float h0 = a0 + b0; h0 = h0 > 0.f ? h0 : 0.f;
    float h1 = a1 + b1; h1 = h1 > 0.f ? h1 : 0.f;
    return h0 * w0 + h1 * w1;
}

__global__ void __launch_bounds__(256)
edge_kernel(const unsigned short* __restrict__ P, const void* __restrict__ ts,
            const float* __restrict__ w2, float* __restrict__ out, int n_edges) {
    const int lane = threadIdx.x & 63;
    const int wid  = threadIdx.x >> 6;
    const int sub  = lane & 7;   // 8 lanes per edge
    const int grp  = lane >> 3;  // 8 edges per wave
    const int gw   = blockIdx.x * 4 + wid;
    const int nw   = gridDim.x * 4;

    const int* ts32 = (const int*)ts;
    const long long* ts64 = (const long long*)ts;
    const bool is64 = detect_is64(ts32, lane);

    const float4 w2a = *reinterpret_cast<const float4*>(w2 + sub * 8);
    const float4 w2b = *reinterpret_cast<const float4*>(w2 + sub * 8 + 4);

    for (int e = gw * 8 + grp; e < n_edges; e += nw * 8) {
        long long s, d;
        if (is64) { s = ts64[2 * e]; d = ts64[2 * e + 1]; }
        else      { s = ts32[2 * e]; d = ts32[2 * e + 1]; }
        const uint4 a = *reinterpret_cast<const uint4*>(P + (size_t)s * 128 + sub * 8);
        const uint4 b = *reinterpret_cast<const uint4*>(P + (size_t)d * 128 + 64 + sub * 8);
        float v = pairterm(a.x, b.x, w2a.x, w2a.y)
                + pairterm(a.y, b.y, w2a.z, w2a.w)
                + pairterm(a.z, b.z, w2b.x, w2b.y)
                + pairterm(a.w, b.w, w2b.z, w2b.w);
#pragma unroll
        for (int off = 1; off < 8; off <<= 1) v += __shfl_xor(v, off);
        if (sub == 0) out[e] = v;
    }
}

// ---------------------------------------------------------------------------
// Fallback (ws too small for P): fused gather + f32 MLP, wave per edge.
__global__ void __launch_bounds__(256)
direct_kernel(const float* __restrict__ emb, const void* __restrict__ ts,
              const float* __restrict__ w1, const float* __restrict__ b1,
              const float* __restrict__ w2, float* __restrict__ out, int n_edges) {
    const int lane = threadIdx.x & 63;
    const int gw   = blockIdx.x * (blockDim.x >> 6) + (threadIdx.x >> 6);
    const int nw   = gridDim.x * (blockDim.x >> 6);
    const float w2v  = w2[lane];
    const float bias = b1[lane];
    const int* ts32 = (const int*)ts;
    const long long* ts64 = (const long long*)ts;
    const bool is64 = detect_is64(ts32, lane);

    for (int e = gw; e < n_edges; e += nw) {
        long long s, d;
        if (is64) { s = ts64[2 * e]; d = ts64[2 * e + 1]; }
        else      { s = ts32[2 * e]; d = ts32[2 * e + 1]; }
        const float4* s4 = reinterpret_cast<const float4*>(emb + s * D_FEAT);
        const float4* d4 = reinterpret_cast<const float4*>(emb + d * D_FEAT);
        float acc = bias;
#pragma unroll
        for (int k4 = 0; k4 < 32; ++k4) {
            float4 r = s4[k4];
            acc += r.x * w1[(4 * k4 + 0) * 64 + lane];
            acc += r.y * w1[(4 * k4 + 1) * 64 + lane];
            acc += r.z * w1[(4 * k4 + 2) * 64 + lane];
            acc += r.w * w1[(4 * k4 + 3) * 64 + lane];
        }
#pragma unroll
        for (int k4 = 0; k4 < 32; ++k4) {
            float4 r = d4[k4];
            acc += r.x * w1[(128 + 4 * k4 + 0) * 64 + lane];
            acc += r.y * w1[(128 + 4 * k4 + 1) * 64 + lane];
            acc += r.z * w1[(128 + 4 * k4 + 2) * 64 + lane];
            acc += r.w * w1[(128 + 4 * k4 + 3) * 64 + lane];
        }
        float h = acc > 0.0f ? acc : 0.0f;
        float v = h * w2v;
#pragma unroll
        for (int off = 32; off > 0; off >>= 1) v += __shfl_xor(v, off);
        if (lane == 0) out[e] = v;
    }
}

// ---------------------------------------------------------------------------
extern "C" void kernel_launch(void* const* d_in, const int* in_sizes, int n_in,
                              void* d_out, int out_size, void* d_ws, size_t ws_size,
                              hipStream_t stream) {
    const float* emb = (const float*)d_in[0];
    const void*  ts  = d_in[1];
    const float* w1  = (const float*)d_in[2];
    const float* b1  = (const float*)d_in[3];
    const float* w2  = (const float*)d_in[4];
    float* out = (float*)d_out;

    const int n_nodes = in_sizes[0] / D_FEAT;   // 100000
    const int n_edges = in_sizes[1] / 2;        // 300000

    const size_t p_bytes = (size_t)n_nodes * 128 * sizeof(unsigned short);

    if (ws_size >= p_bytes) {
        unsigned short* P = (unsigned short*)d_ws;
        // 782 blocks * 4 waves = 3128 waves; 6250 tiles -> ~2 tiles/wave even
        precompute_kernel<<<782, 256, 0, stream>>>(emb, w1, b1, P, n_nodes);
        edge_kernel<<<2048, 256, 0, stream>>>(P, ts, w2, out, n_edges);
    } else {
        direct_kernel<<<2048, 256, 0, stream>>>(emb, ts, w1, b1, w2, out, n_edges);
    }
}

// Round 9
// 37.530 us; speedup vs baseline: 1.1902x; 1.1902x over previous
//
#include <hip/hip_runtime.h>
#include <hip/hip_bf16.h>

// out[e] = relu(concat(emb[src], emb[dst]) @ w1 + b1) @ w2
// Restructure: P[n][j]    = emb[n] . w1[0:128, j]  + b1[j]   (j < 64)
//              P[n][64+j] = emb[n] . w1[128:256, j]          (j < 64)
// out[e] = sum_j relu(P[src][j] + P[dst][64+j]) * w2[j]
// P via bf16 MFMA (16x16x32, swapped operands -> lane holds 4 consecutive
// P-cols of one node), stored bf16.
//
// R9: latency-bound fix, structural. (1) B-fragments (tile-invariant!)
// hoisted to 128 VGPRs once -> zero LDS ops in the tile loop. (2) bf16 pack
// = (u+0x8000)>>16 pair-fused via v_perm_b32: 3 VALU / 2 values (was 5/value
// RNE in R7, worse NaN-checked header cast in R8). (3) grid 512 = exactly
// 2 blocks/CU resident at 2 waves/SIMD (VGPR ~234, launch_bounds(256,2)).

#define D_FEAT 128
#define HIDDEN 64

typedef __attribute__((ext_vector_type(8))) short v8s;      // 8 bf16 (4 VGPRs)
typedef __attribute__((ext_vector_type(4))) float f32x4;    // 4 f32
typedef __attribute__((ext_vector_type(4))) unsigned u32x4; // 4 u32

// round-to-nearest (ties away): bits + 0x8000, take high 16. 2 VALU ops.
__device__ inline unsigned short f2bf_rn(float f) {
    unsigned u = __builtin_bit_cast(unsigned, f) + 0x8000u;
    return (unsigned short)(u >> 16);
}
// pack two f32 -> one u32 of 2 bf16 (lo in low half): 2 adds + 1 v_perm_b32.
__device__ inline unsigned pack2(float lo, float hi) {
    unsigned ul = __builtin_bit_cast(unsigned, lo) + 0x8000u;
    unsigned uh = __builtin_bit_cast(unsigned, hi) + 0x8000u;
    return __builtin_amdgcn_perm(uh, ul, 0x07060302u);  // {uh[31:16],ul[31:16]}
}

// int64-vs-int32 detection: int64 (LE, idx < 2^31) => every odd int32 word 0.
__device__ inline bool detect_is64(const int* ts32, int lane) {
    int probe = ts32[2 * lane + 1];
    return __ballot(probe != 0) == 0ULL;
}

// ---------------------------------------------------------------------------
// Persistent precompute of P (n_nodes x 128, bf16).
__global__ void __launch_bounds__(256, 2)
precompute_kernel(const float* __restrict__ emb, const float* __restrict__ w1,
                  const float* __restrict__ b1, unsigned short* __restrict__ P,
                  int n_nodes) {
    __shared__ unsigned short bt[16384];   // Bt[c][k] at (c*128+k)^((c&7)<<3)
    const int t    = threadIdx.x;
    const int lane = t & 63;
    const int wid  = t >> 6;
    const int sub  = lane & 15;   // node within tile / D col
    const int g    = lane >> 4;   // k-group / D row group

    // ---- build swizzled Bt from w1 (256x64 f32): thread t owns w1 row t.
    {
        const int k    = t & 127;
        const int half = t >> 7;
        const float4* src = reinterpret_cast<const float4*>(w1 + (size_t)t * 64);
#pragma unroll
        for (int j4 = 0; j4 < 16; ++j4) {
            const float4 v = src[j4];
            const int cb = half * 64 + j4 * 4;
            bt[((cb + 0) * 128 + k) ^ (((cb + 0) & 7) << 3)] = f2bf_rn(v.x);
            bt[((cb + 1) * 128 + k) ^ (((cb + 1) & 7) << 3)] = f2bf_rn(v.y);
            bt[((cb + 2) * 128 + k) ^ (((cb + 2) & 7) << 3)] = f2bf_rn(v.z);
            bt[((cb + 3) * 128 + k) ^ (((cb + 3) & 7) << 3)] = f2bf_rn(v.w);
        }
    }

    // bias regs (cols < 64 only, i.e. nj < 4): cols nj*16 + g*4 .. +3
    float4 bias[4];
#pragma unroll
    for (int nj = 0; nj < 4; ++nj)
        bias[nj] = *reinterpret_cast<const float4*>(b1 + nj * 16 + g * 4);

    __syncthreads();   // Bt ready; read-only below

    // ---- hoist ALL B-fragments to registers (tile-invariant): 32 x v8s.
    // Static indices only (unrolled) so this stays in VGPRs, not scratch.
    v8s B[4][8];
#pragma unroll
    for (int ks = 0; ks < 4; ++ks)
#pragma unroll
        for (int nj = 0; nj < 8; ++nj) {
            const int c = nj * 16 + sub;
            const int eidx = (c * 128 + ks * 32 + g * 8) ^ ((c & 7) << 3);
            B[ks][nj] = *reinterpret_cast<const v8s*>(&bt[eidx]);
        }

    const int ntiles = (n_nodes + 15) / 16;
    const int gwave  = blockIdx.x * 4 + wid;
    const int nwave  = gridDim.x * 4;

    auto loadA = [&](float4* a, int tt) {
        int row = tt * 16 + sub;
        if (row >= n_nodes) row = n_nodes - 1;
        const float* p = emb + (size_t)row * D_FEAT + g * 8;
#pragma unroll
        for (int ks = 0; ks < 4; ++ks) {
            a[2 * ks]     = *reinterpret_cast<const float4*>(p + ks * 32);
            a[2 * ks + 1] = *reinterpret_cast<const float4*>(p + ks * 32 + 4);
        }
    };

    float4 A0[8], A1[8];
    if (gwave < ntiles) loadA(A0, gwave);

    for (int tt = gwave; tt < ntiles; tt += nwave) {
        const int tn = tt + nwave;
        if (tn < ntiles) loadA(A1, tn);   // prefetch next tile (raw: no
                                          // dependent ops until next iter)
        f32x4 acc[8];
#pragma unroll
        for (int nj = 0; nj < 8; ++nj) acc[nj] = (f32x4){0.f, 0.f, 0.f, 0.f};

#pragma unroll
        for (int ks = 0; ks < 4; ++ks) {
            const float4 a0 = A0[2 * ks], a1 = A0[2 * ks + 1];
            u32x4 ap;
            ap[0] = pack2(a0.x, a0.y);
            ap[1] = pack2(a0.z, a0.w);
            ap[2] = pack2(a1.x, a1.y);
            ap[3] = pack2(a1.z, a1.w);
            const v8s af = __builtin_bit_cast(v8s, ap);
#pragma unroll
            for (int nj = 0; nj < 8; ++nj)
                // swapped: D[c][node], col=node=sub, row=c_local=g*4+reg
                acc[nj] = __builtin_amdgcn_mfma_f32_16x16x32_bf16(B[ks][nj], af,
                                                                  acc[nj], 0, 0, 0);
        }

        // epilogue: lane holds P cols nj*16+g*4..+3 for node tt*16+sub
        const int node = tt * 16 + sub;
        if (node < n_nodes) {
            unsigned short* prow = P + (size_t)node * 128;
#pragma unroll
            for (int nj = 0; nj < 8; ++nj) {
                float s0 = acc[nj][0], s1 = acc[nj][1];
                float s2 = acc[nj][2], s3 = acc[nj][3];
                if (nj < 4) { s0 += bias[nj].x; s1 += bias[nj].y;
                              s2 += bias[nj].z; s3 += bias[nj].w; }
                uint2 o;
                o.x = pack2(s0, s1);
                o.y = pack2(s2, s3);
                *reinterpret_cast<uint2*>(prow + nj * 16 + g * 4) = o;
            }
        }

#pragma unroll
        for (int i = 0; i < 8; ++i) A0[i] = A1[i];
    }
}

// ---------------------------------------------------------------------------
// Edge pass: 8 lanes per edge, 8 edges per wave. 16B uint4 loads per half,
// bf16 unpack via bit ops, 3-step shuffle reduce. (measured ~9.3 us warm)
__device__ inline float pairterm(unsigned aw, unsigned bw, float w0, float w1) {
    float a0 = __builtin_bit_cast(float, aw << 16);
    float a1 = __builtin_bit_cast(float, aw & 0xFFFF0000u);
    float b0 = __builtin_bit_cast(float, bw << 16);
    float b1 = __builtin_bit_cast(float, bw & 0xFFFF0000u);
    float h0 = a0 + b0; h0 = h0 > 0.f ? h0 : 0.f;
    float h1 = a1 + b1; h1 = h1 > 0.f ? h1 : 0.f;
    return h0 * w0 + h1 * w1;
}

__global__ void __launch_bounds__(256)
edge_kernel(const unsigned short* __restrict__ P, const void* __restrict__ ts,
            const float* __restrict__ w2, float* __restrict__ out, int n_edges) {
    const int lane = threadIdx.x & 63;
    const int wid  = threadIdx.x >> 6;
    const int sub  = lane & 7;   // 8 lanes per edge
    const int grp  = lane >> 3;  // 8 edges per wave
    const int gw   = blockIdx.x * 4 + wid;
    const int nw   = gridDim.x * 4;

    const int* ts32 = (const int*)ts;
    const long long* ts64 = (const long long*)ts;
    const bool is64 = detect_is64(ts32, lane);

    const float4 w2a = *reinterpret_cast<const float4*>(w2 + sub * 8);
    const float4 w2b = *reinterpret_cast<const float4*>(w2 + sub * 8 + 4);

    for (int e = gw * 8 + grp; e < n_edges; e += nw * 8) {
        long long s, d;
        if (is64) { s = ts64[2 * e]; d = ts64[2 * e + 1]; }
        else      { s = ts32[2 * e]; d = ts32[2 * e + 1]; }
        const uint4 a = *reinterpret_cast<const uint4*>(P + (size_t)s * 128 + sub * 8);
        const uint4 b = *reinterpret_cast<const uint4*>(P + (size_t)d * 128 + 64 + sub * 8);
        float v = pairterm(a.x, b.x, w2a.x, w2a.y)
                + pairterm(a.y, b.y, w2a.z, w2a.w)
                + pairterm(a.z, b.z, w2b.x, w2b.y)
                + pairterm(a.w, b.w, w2b.z, w2b.w);
#pragma unroll
        for (int off = 1; off < 8; off <<= 1) v += __shfl_xor(v, off);
        if (sub == 0) out[e] = v;
    }
}

// ---------------------------------------------------------------------------
// Fallback (ws too small for P): fused gather + f32 MLP, wave per edge.
__global__ void __launch_bounds__(256)
direct_kernel(const float* __restrict__ emb, const void* __restrict__ ts,
              const float* __restrict__ w1, const float* __restrict__ b1,
              const float* __restrict__ w2, float* __restrict__ out, int n_edges) {
    const int lane = threadIdx.x & 63;
    const int gw   = blockIdx.x * (blockDim.x >> 6) + (threadIdx.x >> 6);
    const int nw   = gridDim.x * (blockDim.x >> 6);
    const float w2v  = w2[lane];
    const float bias = b1[lane];
    const int* ts32 = (const int*)ts;
    const long long* ts64 = (const long long*)ts;
    const bool is64 = detect_is64(ts32, lane);

    for (int e = gw; e < n_edges; e += nw) {
        long long s, d;
        if (is64) { s = ts64[2 * e]; d = ts64[2 * e + 1]; }
        else      { s = ts32[2 * e]; d = ts32[2 * e + 1]; }
        const float4* s4 = reinterpret_cast<const float4*>(emb + s * D_FEAT);
        const float4* d4 = reinterpret_cast<const float4*>(emb + d * D_FEAT);
        float acc = bias;
#pragma unroll
        for (int k4 = 0; k4 < 32; ++k4) {
            float4 r = s4[k4];
            acc += r.x * w1[(4 * k4 + 0) * 64 + lane];
            acc += r.y * w1[(4 * k4 + 1) * 64 + lane];
            acc += r.z * w1[(4 * k4 + 2) * 64 + lane];
            acc += r.w * w1[(4 * k4 + 3) * 64 + lane];
        }
#pragma unroll
        for (int k4 = 0; k4 < 32; ++k4) {
            float4 r = d4[k4];
            acc += r.x * w1[(128 + 4 * k4 + 0) * 64 + lane];
            acc += r.y * w1[(128 + 4 * k4 + 1) * 64 + lane];
            acc += r.z * w1[(128 + 4 * k4 + 2) * 64 + lane];
            acc += r.w * w1[(128 + 4 * k4 + 3) * 64 + lane];
        }
        float h = acc > 0.0f ? acc : 0.0f;
        float v = h * w2v;
#pragma unroll
        for (int off = 32; off > 0; off >>= 1) v += __shfl_xor(v, off);
        if (lane == 0) out[e] = v;
    }
}

// ---------------------------------------------------------------------------
extern "C" void kernel_launch(void* const* d_in, const int* in_sizes, int n_in,
                              void* d_out, int out_size, void* d_ws, size_t ws_size,
                              hipStream_t stream) {
    const float* emb = (const float*)d_in[0];
    const void*  ts  = d_in[1];
    const float* w1  = (const float*)d_in[2];
    const float* b1  = (const float*)d_in[3];
    const float* w2  = (const float*)d_in[4];
    float* out = (float*)d_out;

    const int n_nodes = in_sizes[0] / D_FEAT;   // 100000
    const int n_edges = in_sizes[1] / 2;        // 300000

    const size_t p_bytes = (size_t)n_nodes * 128 * sizeof(unsigned short);

    if (ws_size >= p_bytes) {
        unsigned short* P = (unsigned short*)d_ws;
        // 512 blocks = exactly 2 blocks/CU resident at 2 waves/SIMD;
        // 6250 tiles / 2048 waves ~= 3 tiles/wave (prefetch covers 2/3).
        precompute_kernel<<<512, 256, 0, stream>>>(emb, w1, b1, P, n_nodes);
        edge_kernel<<<2048, 256, 0, stream>>>(P, ts, w2, out, n_edges);
    } else {
        direct_kernel<<<2048, 256, 0, stream>>>(emb, ts, w1, b1, w2, out, n_edges);
    }
}